// Round 17
// baseline (622.145 us; speedup 1.0000x reference)
//
#include <hip/hip_runtime.h>

#define N0c 100000
#define N1c 25000
#define N2c 5000
#define E0c 400000
#define E1c 80000
// IN_FEATS = N_HIDDEN = 512, N_CLASSES = 64
// M-tiles (128 rows): GEMM1 782, GEMM2 196

typedef __attribute__((ext_vector_type(8))) short bf16x8;
typedef __attribute__((ext_vector_type(4))) float f32x4;

#define GLOAD_LDS(g, l) \
    __builtin_amdgcn_global_load_lds((__attribute__((address_space(1))) const unsigned int*)(const void*)(g), \
                                     (__attribute__((address_space(3))) unsigned int*)(void*)(l), 16, 0, 0)

// round-to-nearest-even bf16 (scalar, for epilogue)
static __device__ __forceinline__ uint rnd_bf(float f) {
    uint u = __float_as_uint(f);
    return (u + 0x7FFFu + ((u >> 16) & 1u)) & 0xFFFF0000u;
}
static __device__ __forceinline__ unsigned short to_bf(float f) {
    return (unsigned short)(rnd_bf(f) >> 16);
}
// HW packed convert: low16 = bf16(f0), high16 = bf16(f1)  (RNE, 1 instr)
static __device__ __forceinline__ uint cvt2bf(float f0, float f1) {
    uint r;
    asm("v_cvt_pk_bf16_f32 %0, %1, %2" : "=v"(r) : "v"(f0), "v"(f1));
    return r;
}

// ---------------------------------------------------------------------------
// Weight pre-convert: W[512][512] fp32 -> bf16 planes.
// Layout: [nh(2)][kt(16)][R(256)][p(4)] 16B slots, p = o ^ ((R>>1)&3)
// (2-way bank aliasing on ds_read_b128 = free, m136).
// ---------------------------------------------------------------------------
__global__ __launch_bounds__(256)
void presplit_w(const float* __restrict__ X, uint4* __restrict__ out)
{
    const int id = blockIdx.x * 256 + threadIdx.x;   // 32768 slots
    const int nh = id >> 14;
    const int rem = id & 16383;
    const int kt = rem >> 10;
    const int sl = rem & 1023;
    const int R = sl >> 2, p = sl & 3;
    const int o = p ^ ((R >> 1) & 3);
    const float* src = X + (size_t)(nh * 256 + R) * 512 + kt * 32 + o * 8;
    float4 x0 = *(const float4*)src;
    float4 x1 = *(const float4*)(src + 4);
    uint4 v;
    v.x = cvt2bf(x0.x, x0.y); v.y = cvt2bf(x0.z, x0.w);
    v.z = cvt2bf(x1.x, x1.y); v.w = cvt2bf(x1.z, x1.w);
    out[id] = v;
}

// ---------------------------------------------------------------------------
// Fused MFMA GEMM (NT): C[M,512] = A[M,512] @ B[512,512]^T.
// Tile 128x256, 8 waves (2M x 4N), BK=32, TRIPLE-BUFFERED counted-vmcnt
// pipeline (T4): per iter {wait vmcnt(N) [tile t lands, t+1 stays in
// flight]; barrier; stage(t+2); ds_read(t); MFMA(t)}.
// N = loads/thread/stage: ASRC0 -> 4 (2 A-fp32 + 2 B), ASRC1 -> 3
// (1 A-bf16 + 2 B). [R16 bug: shared vmcnt(4) under-waited ASRC1 -> NaN.]
// LDS: 3 buffers; ASRC0 = 96 KB (1 block/CU; depth replaces TLP, m218),
// ASRC1 = 72 KB (2 blocks/CU).
//   ASRC 0: A = raw fp32; [r(128)][p(8)] 16B slots, p = sigma(o)^(r&7);
//           fragment reads rp[lg^sw]/rp[(lg+4)^sw] = 2-way = free;
//           fp32->bf16 via v_cvt_pk at fragment-read.
//   ASRC 1: A = bf16 planes [mt][kt(16)][r(128)][p(4)], p = o^((r>>1)&3).
//   B: bf16 planes [nh][kt][R(256)][p(4)], p = o^((R>>1)&3), linear DMA.
// EPI 0: Cb[m*512+n]      = bf16(relu(acc+bias)-hist[m*512+n])
// EPI 1: Cb[m*1024+n]     = bf16((acc+bias)-hist[m*1024+n])
//        Cb[m*1024+512+n] = bf16(relu(acc+bias)-hist[m*1024+512+n])
// ---------------------------------------------------------------------------
template<int ASRC, int EPI>
__global__ __launch_bounds__(512)
void gemm_fused(const float* __restrict__ Af32, const uint4* __restrict__ At,
                const uint4* __restrict__ Bt, const float* __restrict__ bias,
                const float* __restrict__ hist, unsigned short* __restrict__ C,
                int Mreal, int nblk)
{
    constexpr int ABASE = (ASRC == 0) ? 1024 : 512;   // A uint4-slots per buffer
    constexpr int BUF   = ABASE + 1024;               // uint4-slots per buffer
    __shared__ uint4 lds[3 * BUF];

    const int tid = threadIdx.x;
    // XCD-aware bijective swizzle (m204 general form)
    const int orig = blockIdx.x;
    const int xcd = orig & 7, q = nblk >> 3, rr = nblk & 7;
    const int lid = (xcd < rr ? xcd * (q + 1) : rr * (q + 1) + (xcd - rr) * q) + (orig >> 3);
    const int bm = lid >> 1, bnh = lid & 1;

    const int w = tid >> 6, lane = tid & 63;
    const int wm = w >> 2, wn = w & 3;        // wave grid 2M x 4N
    const int lg = lane >> 4, lr = lane & 15;

    // kt-invariant staging coords
    const int s_slot = w * 128 + lane;        // + 64 for second half
    const int s_r0 = s_slot >> 3, s_p0 = s_slot & 7;
    const int s_r1 = (s_slot + 64) >> 3, s_p1 = (s_slot + 64) & 7;

    auto stage = [&](int kt, int base) {
        if (ASRC == 0) {
            {
                const int t = s_p0 ^ (s_r0 & 7);
                const int o = ((t & 3) << 1) | (t >> 2);
                int g = bm * 128 + s_r0; if (g > Mreal - 1) g = Mreal - 1;
                GLOAD_LDS(Af32 + (size_t)g * 512 + kt * 32 + o * 4, &lds[base + s_slot]);
            }
            {
                const int t = s_p1 ^ (s_r1 & 7);
                const int o = ((t & 3) << 1) | (t >> 2);
                int g = bm * 128 + s_r1; if (g > Mreal - 1) g = Mreal - 1;
                GLOAD_LDS(Af32 + (size_t)g * 512 + kt * 32 + o * 4, &lds[base + s_slot + 64]);
            }
        } else {
            GLOAD_LDS(At + ((size_t)bm * 16 + kt) * 512 + tid, &lds[base + tid]);
        }
        const uint4* Bsrc = Bt + ((size_t)bnh * 16 + kt) * 1024;
        GLOAD_LDS(Bsrc + s_slot, &lds[base + ABASE + s_slot]);
        GLOAD_LDS(Bsrc + s_slot + 64, &lds[base + ABASE + s_slot + 64]);
    };

    f32x4 acc[4][4];
#pragma unroll
    for (int i = 0; i < 4; ++i)
#pragma unroll
        for (int j = 0; j < 4; ++j) acc[i][j] = {0.f, 0.f, 0.f, 0.f};

    // prologue: stage tiles 0 and 1 (per-thread outstanding = 2N)
    stage(0, 0);
    stage(1, BUF);
    asm volatile("" ::: "memory");

    int base_t = 0;                // buffer base of tile kt (rotates 0,BUF,2BUF)
    for (int kt = 0; kt < 16; ++kt) {
        // counted wait: completes tile kt, leaves kt+1 in flight (m218/T4).
        // N must equal loads/thread/stage for THIS variant (R16 lesson).
        if (kt < 15) {
            if constexpr (ASRC == 0) asm volatile("s_waitcnt vmcnt(4)" ::: "memory");
            else                     asm volatile("s_waitcnt vmcnt(3)" ::: "memory");
        } else {
            asm volatile("s_waitcnt vmcnt(0)" ::: "memory");
        }
        __builtin_amdgcn_s_barrier();
        asm volatile("" ::: "memory");

        // stage tile kt+2 into the buffer last read at iter kt-1 (safe: all
        // waves passed this iter's barrier => done reading it)
        if (kt < 14) {
            int b2 = base_t + 2 * BUF; if (b2 >= 3 * BUF) b2 -= 3 * BUF;
            stage(kt + 2, b2);
        }
        const int cb = base_t;
        base_t += BUF; if (base_t >= 3 * BUF) base_t = 0;

        bf16x8 a[4], b[4];
#pragma unroll
        for (int mi = 0; mi < 4; ++mi) {
            const int r = wm * 64 + mi * 16 + lr;
            if (ASRC == 0) {
                const int sw = r & 7;
                const uint4* rp = &lds[cb + r * 8];
                const f32x4 q0 = *(const f32x4*)&rp[lg ^ sw];
                const f32x4 q1 = *(const f32x4*)&rp[(lg + 4) ^ sw];
                uint4 v;
                v.x = cvt2bf(q0[0], q0[1]); v.y = cvt2bf(q0[2], q0[3]);
                v.z = cvt2bf(q1[0], q1[1]); v.w = cvt2bf(q1[2], q1[3]);
                a[mi] = *(const bf16x8*)&v;
            } else {
                a[mi] = *(const bf16x8*)&lds[cb + r * 4 + (lg ^ ((r >> 1) & 3))];
            }
        }
#pragma unroll
        for (int ni = 0; ni < 4; ++ni) {
            const int R = wn * 64 + ni * 16 + lr;
            b[ni] = *(const bf16x8*)&lds[cb + ABASE + R * 4 + (lg ^ ((R >> 1) & 3))];
        }
#pragma unroll
        for (int mi = 0; mi < 4; ++mi)
#pragma unroll
            for (int ni = 0; ni < 4; ++ni)
                acc[mi][ni] = __builtin_amdgcn_mfma_f32_16x16x32_bf16(
                    a[mi], b[ni], acc[mi][ni], 0, 0, 0);
    }

    // epilogue: C/D layout col=lane&15, row=(lane>>4)*4+reg  (m89)
#pragma unroll
    for (int mi = 0; mi < 4; ++mi)
#pragma unroll
        for (int ni = 0; ni < 4; ++ni) {
            const int col = bnh * 256 + wn * 64 + ni * 16 + lr;
            const float bv = bias[col];
#pragma unroll
            for (int r = 0; r < 4; ++r) {
                const int m = bm * 128 + wm * 64 + mi * 16 + lg * 4 + r;
                if (m < Mreal) {
                    const float v = acc[mi][ni][r] + bv;
                    if (EPI == 0) {
                        C[(size_t)m * 512 + col] = to_bf(fmaxf(v, 0.f) - hist[(size_t)m * 512 + col]);
                    } else {
                        C[(size_t)m * 1024 + col]       = to_bf(v - hist[(size_t)m * 1024 + col]);
                        C[(size_t)m * 1024 + 512 + col] = to_bf(fmaxf(v, 0.f) - hist[(size_t)m * 1024 + 512 + col]);
                    }
                }
            }
        }
}

// ---------------------------------------------------------------------------
// Small GEMM: out[M,64] = A[M,1024] @ B[64,1024]^T + bias  (fp32 classifier)
// ---------------------------------------------------------------------------
__global__ __launch_bounds__(256)
void gemm64(const float* __restrict__ A, const float* __restrict__ B,
            const float* __restrict__ bias, float* __restrict__ C, int M)
{
    const int K = 1024;
    __shared__ float As[32][68];
    __shared__ float Bs[32][68];
    const int tid = threadIdx.x;
    const int tx = tid & 15, ty = tid >> 4;
    const int lrow = tid >> 3;
    const int lk   = (tid & 7) * 4;
    const int bm = blockIdx.x;

    float acc[4][4];
#pragma unroll
    for (int i = 0; i < 4; ++i)
#pragma unroll
        for (int j = 0; j < 4; ++j) acc[i][j] = 0.f;

    int ar0 = bm * 64 + lrow;      if (ar0 > M - 1) ar0 = M - 1;
    int ar1 = bm * 64 + 32 + lrow; if (ar1 > M - 1) ar1 = M - 1;

    for (int kt = 0; kt < K; kt += 32) {
        float4 a0 = *(const float4*)(A + (size_t)ar0 * K + kt + lk);
        float4 a1 = *(const float4*)(A + (size_t)ar1 * K + kt + lk);
        float4 b0 = *(const float4*)(B + (size_t)lrow * K + kt + lk);
        float4 b1 = *(const float4*)(B + (size_t)(32 + lrow) * K + kt + lk);
        __syncthreads();
        As[lk+0][lrow]    = a0.x; As[lk+1][lrow]    = a0.y; As[lk+2][lrow]    = a0.z; As[lk+3][lrow]    = a0.w;
        As[lk+0][lrow+32] = a1.x; As[lk+1][lrow+32] = a1.y; As[lk+2][lrow+32] = a1.z; As[lk+3][lrow+32] = a1.w;
        Bs[lk+0][lrow]    = b0.x; Bs[lk+1][lrow]    = b0.y; Bs[lk+2][lrow]    = b0.z; Bs[lk+3][lrow]    = b0.w;
        Bs[lk+0][lrow+32] = b1.x; Bs[lk+1][lrow+32] = b1.y; Bs[lk+2][lrow+32] = b1.z; Bs[lk+3][lrow+32] = b1.w;
        __syncthreads();
#pragma unroll
        for (int kk = 0; kk < 32; ++kk) {
            float4 av = *(const float4*)&As[kk][ty * 4];
            float4 bv = *(const float4*)&Bs[kk][tx * 4];
            float aa[4] = {av.x, av.y, av.z, av.w};
            float bb[4] = {bv.x, bv.y, bv.z, bv.w};
#pragma unroll
            for (int i = 0; i < 4; ++i)
#pragma unroll
                for (int j = 0; j < 4; ++j)
                    acc[i][j] += aa[i] * bb[j];
        }
    }

    const float4 bv = *(const float4*)&bias[tx * 4];
#pragma unroll
    for (int i = 0; i < 4; ++i) {
        const int m = bm * 64 + ty * 4 + i;
        if (m >= M) continue;
        float4 o;
        o.x = acc[i][0] + bv.x; o.y = acc[i][1] + bv.y;
        o.z = acc[i][2] + bv.z; o.w = acc[i][3] + bv.w;
        *(float4*)&C[(size_t)m * 64 + tx * 4] = o;
    }
}

// ---------------------------------------------------------------------------
// CSR build: degree count -> exclusive scan -> edge scatter
// ---------------------------------------------------------------------------
__global__ void count_deg(const int* __restrict__ dst, int* __restrict__ deg, int E)
{
    int e = blockIdx.x * blockDim.x + threadIdx.x;
    if (e < E) atomicAdd(&deg[dst[e]], 1);
}

__global__ __launch_bounds__(1024)
void exscan(const int* __restrict__ deg, int* __restrict__ off, int* __restrict__ cur, int n)
{
    __shared__ int wsum[16];
    __shared__ int carry;
    const int tid = threadIdx.x, lane = tid & 63, w = tid >> 6;
    if (tid == 0) carry = 0;
    __syncthreads();
    for (int base = 0; base < n; base += 1024) {
        const int i = base + tid;
        const int v = (i < n) ? deg[i] : 0;
        int x = v;
#pragma unroll
        for (int d = 1; d < 64; d <<= 1) {
            int y = __shfl_up(x, d, 64);
            if (lane >= d) x += y;
        }
        if (lane == 63) wsum[w] = x;
        __syncthreads();
        int wo = 0, tot = 0;
#pragma unroll
        for (int k = 0; k < 16; ++k) { int s = wsum[k]; tot += s; if (k < w) wo += s; }
        const int excl = carry + wo + x - v;
        if (i < n) { off[i] = excl; cur[i] = excl; }
        __syncthreads();
        if (tid == 0) carry += tot;
        __syncthreads();
    }
    if (tid == 0) off[n] = carry;
}

__global__ void scatter_edges(const int* __restrict__ src, const int* __restrict__ dst,
                              int* __restrict__ cur, int* __restrict__ eidx, int E)
{
    int e = blockIdx.x * blockDim.x + threadIdx.x;
    if (e < E) {
        int p = atomicAdd(&cur[dst[e]], 1);
        eidx[p] = src[e];
    }
}

// ---------------------------------------------------------------------------
// Segment mean over bf16 h (D=512) + fp32 residual add; writes GEMM2's
// A-planes [mt][kt(16)][r(128)][p(4)], p = o^((r>>1)&3). One wave per dst
// row; lane owns k = lane*8..+7  (kt = lane>>2, o = lane&3).
// ---------------------------------------------------------------------------
__global__ __launch_bounds__(256)
void seg_mean_split(const unsigned short* __restrict__ h, const int* __restrict__ off,
                    const int* __restrict__ eidx, const float* __restrict__ addin,
                    uint4* __restrict__ out, int n_dst, int n_pad)
{
    const int wid = blockIdx.x * 4 + (threadIdx.x >> 6);
    const int lane = threadIdx.x & 63;
    if (wid >= n_pad) return;
    uint4 v = {0u, 0u, 0u, 0u};
    if (wid < n_dst) {
        const int e0 = off[wid], e1 = off[wid + 1];
        float s[8];
#pragma unroll
        for (int i = 0; i < 8; ++i) s[i] = 0.f;
        for (int e = e0; e < e1; ++e) {
            const uint4 vv = *((const uint4*)(h + (size_t)eidx[e] * 512) + lane);
            const uint u[4] = {vv.x, vv.y, vv.z, vv.w};
#pragma unroll
            for (int i = 0; i < 4; ++i) {
                s[2 * i]     += __uint_as_float(u[i] << 16);
                s[2 * i + 1] += __uint_as_float(u[i] & 0xFFFF0000u);
            }
        }
        const float sc = 1.0f / (float)((e1 - e0) > 0 ? (e1 - e0) : 1);
        const float* ad = addin + (size_t)wid * 512 + lane * 8;
        float4 d0 = *(const float4*)ad;
        float4 d1 = *(const float4*)(ad + 4);
        v.x = cvt2bf(s[0] * sc + d0.x, s[1] * sc + d0.y);
        v.y = cvt2bf(s[2] * sc + d0.z, s[3] * sc + d0.w);
        v.z = cvt2bf(s[4] * sc + d1.x, s[5] * sc + d1.y);
        v.w = cvt2bf(s[6] * sc + d1.z, s[7] * sc + d1.w);
    }
    const int mt = wid >> 7, r = wid & 127;
    const int kt = lane >> 2, o = lane & 3;
    out[((size_t)mt * 16 + kt) * 512 + r * 4 + (o ^ ((r >> 1) & 3))] = v;
}

// ---------------------------------------------------------------------------
// Segment mean over bf16 h (D=1024) + fp32 residual add -> fp32 out (agg1)
// ---------------------------------------------------------------------------
__global__ __launch_bounds__(256)
void seg_mean_add4(const unsigned short* __restrict__ h, const int* __restrict__ off,
                   const int* __restrict__ eidx, const float* __restrict__ addin,
                   float* __restrict__ out, int n_dst)
{
    const int wid = blockIdx.x * 4 + (threadIdx.x >> 6);
    const int lane = threadIdx.x & 63;
    if (wid >= n_dst) return;
    const int e0 = off[wid], e1 = off[wid + 1];
    float s[16];
#pragma unroll
    for (int i = 0; i < 16; ++i) s[i] = 0.f;
    for (int e = e0; e < e1; ++e) {
        const uint4* row = (const uint4*)(h + (size_t)eidx[e] * 1024);
#pragma unroll
        for (int half = 0; half < 2; ++half) {
            const uint4 v = row[lane + 64 * half];
            const uint u[4] = {v.x, v.y, v.z, v.w};
#pragma unroll
            for (int i = 0; i < 4; ++i) {
                s[8 * half + 2 * i]     += __uint_as_float(u[i] << 16);
                s[8 * half + 2 * i + 1] += __uint_as_float(u[i] & 0xFFFF0000u);
            }
        }
    }
    const float sc = 1.0f / (float)((e1 - e0) > 0 ? (e1 - e0) : 1);
#pragma unroll
    for (int half = 0; half < 2; ++half) {
        const float* ad = addin + (size_t)wid * 1024 + half * 512 + lane * 8;
        float* o = out + (size_t)wid * 1024 + half * 512 + lane * 8;
        float4 d0 = *(const float4*)ad;
        float4 d1 = *(const float4*)(ad + 4);
        float4 r0, r1;
        r0.x = s[8*half+0] * sc + d0.x; r0.y = s[8*half+1] * sc + d0.y;
        r0.z = s[8*half+2] * sc + d0.z; r0.w = s[8*half+3] * sc + d0.w;
        r1.x = s[8*half+4] * sc + d1.x; r1.y = s[8*half+5] * sc + d1.y;
        r1.z = s[8*half+6] * sc + d1.z; r1.w = s[8*half+7] * sc + d1.w;
        *(float4*)o = r0;
        *(float4*)(o + 4) = r1;
    }
}

// ---------------------------------------------------------------------------
extern "C" void kernel_launch(void* const* d_in, const int* in_sizes, int n_in,
                              void* d_out, int out_size, void* d_ws, size_t ws_size,
                              hipStream_t stream)
{
    const float* feats   = (const float*)d_in[0];
    const float* h0_hist = (const float*)d_in[1];
    const float* agg_h0  = (const float*)d_in[2];
    const float* h1_hist = (const float*)d_in[3];
    const float* agg_h1  = (const float*)d_in[4];
    const float* W0 = (const float*)d_in[5];
    const float* b0 = (const float*)d_in[6];
    const float* W1 = (const float*)d_in[7];
    const float* b1 = (const float*)d_in[8];
    const float* W2 = (const float*)d_in[9];
    const float* b2 = (const float*)d_in[10];
    const int* src0 = (const int*)d_in[11];
    const int* dst0 = (const int*)d_in[12];
    const int* src1 = (const int*)d_in[13];
    const int* dst1 = (const int*)d_in[14];

    const int MT1 = 782;                       // ceil(100000/128)
    const int MT2 = 196;                       // ceil(25000/128)

    const size_t h0B   = ((size_t)N0c * 512 * 2 + 255) & ~(size_t)255;   // bf16 h0 (h1cat overlays)
    const size_t a2B   = (size_t)MT2 * 16 * 512 * 16;                    // 25.7 MB (A2 planes)
    const size_t agg1B = (size_t)N2c * 1024 * 4;                         // 20.5 MB
    const size_t wsB   = 32768 * 16;                                     // 512 KB per weight plane

    char* ws = (char*)d_ws;
    unsigned short* h0 = (unsigned short*)ws;
    unsigned short* h1cat = h0;                              ws += h0B;
    uint4* A2s    = (uint4*)ws;                              ws += a2B;
    float* agg1   = (float*)ws;                              ws += agg1B;
    uint4* Ws0    = (uint4*)ws;                              ws += wsB;
    uint4* Ws1    = (uint4*)ws;                              ws += wsB;
    int* deg0  = (int*)ws;  ws += sizeof(int) * N1c;
    int* off0  = (int*)ws;  ws += sizeof(int) * (N1c + 1);
    int* cur0  = (int*)ws;  ws += sizeof(int) * N1c;
    int* eidx0 = (int*)ws;  ws += sizeof(int) * E0c;
    int* deg1  = (int*)ws;  ws += sizeof(int) * N2c;
    int* off1  = (int*)ws;  ws += sizeof(int) * (N2c + 1);
    int* cur1  = (int*)ws;  ws += sizeof(int) * N2c;
    int* eidx1 = (int*)ws;

    hipMemsetAsync(deg0, 0, sizeof(int) * N1c, stream);
    hipMemsetAsync(deg1, 0, sizeof(int) * N2c, stream);

    // weight planes + CSR level 0 (independent of GEMM1)
    presplit_w<<<128, 256, 0, stream>>>(W0, Ws0);
    presplit_w<<<128, 256, 0, stream>>>(W1, Ws1);
    count_deg<<<(E0c + 255) / 256, 256, 0, stream>>>(dst0, deg0, E0c);
    exscan<<<1, 1024, 0, stream>>>(deg0, off0, cur0, N1c);
    scatter_edges<<<(E0c + 255) / 256, 256, 0, stream>>>(src0, dst0, cur0, eidx0, E0c);

    // layer 0: h0 = bf16(relu(feats @ W0^T + b0) - h0_hist)
    // A = raw fp32 feats staged by DMA (permuted source), cvt at fragment-read
    gemm_fused<0, 0><<<MT1 * 2, 512, 0, stream>>>(feats, nullptr, Ws0, b0, h0_hist, h0, N0c, MT1 * 2);

    // agg0 = segment_mean(h0) + agg_h0, written as GEMM2 A-planes
    seg_mean_split<<<(MT2 * 128) / 4, 256, 0, stream>>>(h0, off0, eidx0, agg_h0, A2s, N1c, MT2 * 128);

    // CSR level 1
    count_deg<<<(E1c + 255) / 256, 256, 0, stream>>>(dst1, deg1, E1c);
    exscan<<<1, 1024, 0, stream>>>(deg1, off1, cur1, N2c);
    scatter_edges<<<(E1c + 255) / 256, 256, 0, stream>>>(src1, dst1, cur1, eidx1, E1c);

    // layer 1: h1cat = bf16([h1 | relu(h1)] - h1_hist), h1 = agg0 @ W1^T + b1
    gemm_fused<1, 1><<<MT2 * 2, 512, 0, stream>>>(nullptr, A2s, Ws1, b1, h1_hist, h1cat, N1c, MT2 * 2);

    // agg1 = segment_mean(h1cat) + agg_h1  (fp32)
    seg_mean_add4<<<(N2c + 3) / 4, 256, 0, stream>>>(h1cat, off1, eidx1, agg_h1, agg1, N2c);

    // classifier: out = agg1 @ W2^T + b2
    gemm64<<<(N2c + 63) / 64, 256, 0, stream>>>(agg1, W2, b2, (float*)d_out, N2c);
}

// Round 18
// 556.244 us; speedup vs baseline: 1.1185x; 1.1185x over previous
//
#include <hip/hip_runtime.h>

#define N0c 100000
#define N1c 25000
#define N2c 5000
#define E0c 400000
#define E1c 80000
// IN_FEATS = N_HIDDEN = 512, N_CLASSES = 64
// M-tiles (128 rows): GEMM1 782, GEMM2 196

typedef __attribute__((ext_vector_type(8))) short bf16x8;
typedef __attribute__((ext_vector_type(4))) float f32x4;

#define GLOAD_LDS(g, l) \
    __builtin_amdgcn_global_load_lds((__attribute__((address_space(1))) const unsigned int*)(const void*)(g), \
                                     (__attribute__((address_space(3))) unsigned int*)(void*)(l), 16, 0, 0)

// round-to-nearest-even bf16 (scalar, for epilogue)
static __device__ __forceinline__ uint rnd_bf(float f) {
    uint u = __float_as_uint(f);
    return (u + 0x7FFFu + ((u >> 16) & 1u)) & 0xFFFF0000u;
}
static __device__ __forceinline__ unsigned short to_bf(float f) {
    return (unsigned short)(rnd_bf(f) >> 16);
}
// HW packed convert: low16 = bf16(f0), high16 = bf16(f1)  (RNE, 1 instr)
static __device__ __forceinline__ uint cvt2bf(float f0, float f1) {
    uint r;
    asm("v_cvt_pk_bf16_f32 %0, %1, %2" : "=v"(r) : "v"(f0), "v"(f1));
    return r;
}

// ---------------------------------------------------------------------------
// Weight pre-convert: W[512][512] fp32 -> bf16 planes.
// Layout: [nh(2)][kt(16)][R(256)][p(4)] 16B slots, p = o ^ ((R>>1)&3)
// (2-way bank aliasing on ds_read_b128 = free, m136).
// ---------------------------------------------------------------------------
__global__ __launch_bounds__(256)
void presplit_w(const float* __restrict__ X, uint4* __restrict__ out)
{
    const int id = blockIdx.x * 256 + threadIdx.x;   // 32768 slots
    const int nh = id >> 14;
    const int rem = id & 16383;
    const int kt = rem >> 10;
    const int sl = rem & 1023;
    const int R = sl >> 2, p = sl & 3;
    const int o = p ^ ((R >> 1) & 3);
    const float* src = X + (size_t)(nh * 256 + R) * 512 + kt * 32 + o * 8;
    float4 x0 = *(const float4*)src;
    float4 x1 = *(const float4*)(src + 4);
    uint4 v;
    v.x = cvt2bf(x0.x, x0.y); v.y = cvt2bf(x0.z, x0.w);
    v.z = cvt2bf(x1.x, x1.y); v.w = cvt2bf(x1.z, x1.w);
    out[id] = v;
}

// ---------------------------------------------------------------------------
// Fused MFMA GEMM (NT): C[M,512] = A[M,512] @ B[512,512]^T.
// R15-proven structure (best measured: GEMM1 257us): tile 128x256, 8 waves
// (2M x 4N), BK=32, DOUBLE-buffered, per iter {STAGE(t+1); ds_read(t);
// setprio(1) MFMA(t) setprio(0); vmcnt(0)+barrier}. 64 KB LDS (ASRC0) ->
// 2 blocks/CU; latency hidden by cross-block TLP + stage-under-compute.
// [R17 measured: 3-buf counted-vmcnt at 96KB/1 block/CU = +23% SLOWER.]
//   ASRC 0: A = raw fp32; [r(128)][p(8)] 16B slots, p = sigma(o)^(r&7);
//           fragment reads rp[lg^sw]/rp[(lg+4)^sw] = 2-way = free;
//           fp32->bf16 via v_cvt_pk at fragment-read.
//   ASRC 1: A = bf16 planes [mt][kt(16)][r(128)][p(4)], p = o^((r>>1)&3).
//   B: bf16 planes [nh][kt][R(256)][p(4)], p = o^((R>>1)&3), linear DMA.
// EPI 0: Cb[m*512+n]      = bf16(relu(acc+bias)-hist[m*512+n])
// EPI 1: Cb[m*1024+n]     = bf16((acc+bias)-hist[m*1024+n])
//        Cb[m*1024+512+n] = bf16(relu(acc+bias)-hist[m*1024+512+n])
// ---------------------------------------------------------------------------
template<int ASRC, int EPI>
__global__ __launch_bounds__(512)
void gemm_fused(const float* __restrict__ Af32, const uint4* __restrict__ At,
                const uint4* __restrict__ Bt, const float* __restrict__ bias,
                const float* __restrict__ hist, unsigned short* __restrict__ C,
                int Mreal, int nblk)
{
    constexpr int ABASE = (ASRC == 0) ? 1024 : 512;   // A uint4-slots per buffer
    constexpr int BUF   = ABASE + 1024;               // uint4-slots per buffer
    __shared__ uint4 lds[2 * BUF];

    const int tid = threadIdx.x;
    // XCD-aware bijective swizzle (m204 general form)
    const int orig = blockIdx.x;
    const int xcd = orig & 7, q = nblk >> 3, rr = nblk & 7;
    const int lid = (xcd < rr ? xcd * (q + 1) : rr * (q + 1) + (xcd - rr) * q) + (orig >> 3);
    const int bm = lid >> 1, bnh = lid & 1;

    const int w = tid >> 6, lane = tid & 63;
    const int wm = w >> 2, wn = w & 3;        // wave grid 2M x 4N
    const int lg = lane >> 4, lr = lane & 15;

    // kt-invariant staging coords
    const int s_slot = w * 128 + lane;        // + 64 for second half
    const int s_r0 = s_slot >> 3, s_p0 = s_slot & 7;
    const int s_r1 = (s_slot + 64) >> 3, s_p1 = (s_slot + 64) & 7;

    auto stage = [&](int kt, int base) {
        if (ASRC == 0) {
            {
                const int t = s_p0 ^ (s_r0 & 7);
                const int o = ((t & 3) << 1) | (t >> 2);
                int g = bm * 128 + s_r0; if (g > Mreal - 1) g = Mreal - 1;
                GLOAD_LDS(Af32 + (size_t)g * 512 + kt * 32 + o * 4, &lds[base + s_slot]);
            }
            {
                const int t = s_p1 ^ (s_r1 & 7);
                const int o = ((t & 3) << 1) | (t >> 2);
                int g = bm * 128 + s_r1; if (g > Mreal - 1) g = Mreal - 1;
                GLOAD_LDS(Af32 + (size_t)g * 512 + kt * 32 + o * 4, &lds[base + s_slot + 64]);
            }
        } else {
            GLOAD_LDS(At + ((size_t)bm * 16 + kt) * 512 + tid, &lds[base + tid]);
        }
        const uint4* Bsrc = Bt + ((size_t)bnh * 16 + kt) * 1024;
        GLOAD_LDS(Bsrc + s_slot, &lds[base + ABASE + s_slot]);
        GLOAD_LDS(Bsrc + s_slot + 64, &lds[base + ABASE + s_slot + 64]);
    };

    f32x4 acc[4][4];
#pragma unroll
    for (int i = 0; i < 4; ++i)
#pragma unroll
        for (int j = 0; j < 4; ++j) acc[i][j] = {0.f, 0.f, 0.f, 0.f};

    // prologue: stage tile 0 -> buf0, drain, sync
    stage(0, 0);
    asm volatile("s_waitcnt vmcnt(0)" ::: "memory");
    __builtin_amdgcn_s_barrier();
    asm volatile("" ::: "memory");

    for (int kt = 0; kt < 16; ++kt) {
        const int cb = (kt & 1) * BUF;
        if (kt < 15) stage(kt + 1, ((kt + 1) & 1) * BUF);   // issue early

        bf16x8 a[4], b[4];
#pragma unroll
        for (int mi = 0; mi < 4; ++mi) {
            const int r = wm * 64 + mi * 16 + lr;
            if (ASRC == 0) {
                const int sw = r & 7;
                const uint4* rp = &lds[cb + r * 8];
                const f32x4 q0 = *(const f32x4*)&rp[lg ^ sw];
                const f32x4 q1 = *(const f32x4*)&rp[(lg + 4) ^ sw];
                uint4 v;
                v.x = cvt2bf(q0[0], q0[1]); v.y = cvt2bf(q0[2], q0[3]);
                v.z = cvt2bf(q1[0], q1[1]); v.w = cvt2bf(q1[2], q1[3]);
                a[mi] = *(const bf16x8*)&v;
            } else {
                a[mi] = *(const bf16x8*)&lds[cb + r * 4 + (lg ^ ((r >> 1) & 3))];
            }
        }
#pragma unroll
        for (int ni = 0; ni < 4; ++ni) {
            const int R = wn * 64 + ni * 16 + lr;
            b[ni] = *(const bf16x8*)&lds[cb + ABASE + R * 4 + (lg ^ ((R >> 1) & 3))];
        }
        __builtin_amdgcn_s_setprio(1);      // T5: favor MFMA-entering wave
#pragma unroll
        for (int mi = 0; mi < 4; ++mi)
#pragma unroll
            for (int ni = 0; ni < 4; ++ni)
                acc[mi][ni] = __builtin_amdgcn_mfma_f32_16x16x32_bf16(
                    a[mi], b[ni], acc[mi][ni], 0, 0, 0);
        __builtin_amdgcn_s_setprio(0);

        if (kt < 15) {
            asm volatile("s_waitcnt vmcnt(0)" ::: "memory");   // next tile landed
            __builtin_amdgcn_s_barrier();
            asm volatile("" ::: "memory");
        }
    }

    // epilogue: C/D layout col=lane&15, row=(lane>>4)*4+reg  (m89)
#pragma unroll
    for (int mi = 0; mi < 4; ++mi)
#pragma unroll
        for (int ni = 0; ni < 4; ++ni) {
            const int col = bnh * 256 + wn * 64 + ni * 16 + lr;
            const float bv = bias[col];
#pragma unroll
            for (int r = 0; r < 4; ++r) {
                const int m = bm * 128 + wm * 64 + mi * 16 + lg * 4 + r;
                if (m < Mreal) {
                    const float v = acc[mi][ni][r] + bv;
                    if (EPI == 0) {
                        C[(size_t)m * 512 + col] = to_bf(fmaxf(v, 0.f) - hist[(size_t)m * 512 + col]);
                    } else {
                        C[(size_t)m * 1024 + col]       = to_bf(v - hist[(size_t)m * 1024 + col]);
                        C[(size_t)m * 1024 + 512 + col] = to_bf(fmaxf(v, 0.f) - hist[(size_t)m * 1024 + 512 + col]);
                    }
                }
            }
        }
}

// ---------------------------------------------------------------------------
// Small GEMM: out[M,64] = A[M,1024] @ B[64,1024]^T + bias  (fp32 classifier)
// ---------------------------------------------------------------------------
__global__ __launch_bounds__(256)
void gemm64(const float* __restrict__ A, const float* __restrict__ B,
            const float* __restrict__ bias, float* __restrict__ C, int M)
{
    const int K = 1024;
    __shared__ float As[32][68];
    __shared__ float Bs[32][68];
    const int tid = threadIdx.x;
    const int tx = tid & 15, ty = tid >> 4;
    const int lrow = tid >> 3;
    const int lk   = (tid & 7) * 4;
    const int bm = blockIdx.x;

    float acc[4][4];
#pragma unroll
    for (int i = 0; i < 4; ++i)
#pragma unroll
        for (int j = 0; j < 4; ++j) acc[i][j] = 0.f;

    int ar0 = bm * 64 + lrow;      if (ar0 > M - 1) ar0 = M - 1;
    int ar1 = bm * 64 + 32 + lrow; if (ar1 > M - 1) ar1 = M - 1;

    for (int kt = 0; kt < K; kt += 32) {
        float4 a0 = *(const float4*)(A + (size_t)ar0 * K + kt + lk);
        float4 a1 = *(const float4*)(A + (size_t)ar1 * K + kt + lk);
        float4 b0 = *(const float4*)(B + (size_t)lrow * K + kt + lk);
        float4 b1 = *(const float4*)(B + (size_t)(32 + lrow) * K + kt + lk);
        __syncthreads();
        As[lk+0][lrow]    = a0.x; As[lk+1][lrow]    = a0.y; As[lk+2][lrow]    = a0.z; As[lk+3][lrow]    = a0.w;
        As[lk+0][lrow+32] = a1.x; As[lk+1][lrow+32] = a1.y; As[lk+2][lrow+32] = a1.z; As[lk+3][lrow+32] = a1.w;
        Bs[lk+0][lrow]    = b0.x; Bs[lk+1][lrow]    = b0.y; Bs[lk+2][lrow]    = b0.z; Bs[lk+3][lrow]    = b0.w;
        Bs[lk+0][lrow+32] = b1.x; Bs[lk+1][lrow+32] = b1.y; Bs[lk+2][lrow+32] = b1.z; Bs[lk+3][lrow+32] = b1.w;
        __syncthreads();
#pragma unroll
        for (int kk = 0; kk < 32; ++kk) {
            float4 av = *(const float4*)&As[kk][ty * 4];
            float4 bv = *(const float4*)&Bs[kk][tx * 4];
            float aa[4] = {av.x, av.y, av.z, av.w};
            float bb[4] = {bv.x, bv.y, bv.z, bv.w};
#pragma unroll
            for (int i = 0; i < 4; ++i)
#pragma unroll
                for (int j = 0; j < 4; ++j)
                    acc[i][j] += aa[i] * bb[j];
        }
    }

    const float4 bv = *(const float4*)&bias[tx * 4];
#pragma unroll
    for (int i = 0; i < 4; ++i) {
        const int m = bm * 64 + ty * 4 + i;
        if (m >= M) continue;
        float4 o;
        o.x = acc[i][0] + bv.x; o.y = acc[i][1] + bv.y;
        o.z = acc[i][2] + bv.z; o.w = acc[i][3] + bv.w;
        *(float4*)&C[(size_t)m * 64 + tx * 4] = o;
    }
}

// ---------------------------------------------------------------------------
// CSR build: degree count -> exclusive scan -> edge scatter
// ---------------------------------------------------------------------------
__global__ void count_deg(const int* __restrict__ dst, int* __restrict__ deg, int E)
{
    int e = blockIdx.x * blockDim.x + threadIdx.x;
    if (e < E) atomicAdd(&deg[dst[e]], 1);
}

__global__ __launch_bounds__(1024)
void exscan(const int* __restrict__ deg, int* __restrict__ off, int* __restrict__ cur, int n)
{
    __shared__ int wsum[16];
    __shared__ int carry;
    const int tid = threadIdx.x, lane = tid & 63, w = tid >> 6;
    if (tid == 0) carry = 0;
    __syncthreads();
    for (int base = 0; base < n; base += 1024) {
        const int i = base + tid;
        const int v = (i < n) ? deg[i] : 0;
        int x = v;
#pragma unroll
        for (int d = 1; d < 64; d <<= 1) {
            int y = __shfl_up(x, d, 64);
            if (lane >= d) x += y;
        }
        if (lane == 63) wsum[w] = x;
        __syncthreads();
        int wo = 0, tot = 0;
#pragma unroll
        for (int k = 0; k < 16; ++k) { int s = wsum[k]; tot += s; if (k < w) wo += s; }
        const int excl = carry + wo + x - v;
        if (i < n) { off[i] = excl; cur[i] = excl; }
        __syncthreads();
        if (tid == 0) carry += tot;
        __syncthreads();
    }
    if (tid == 0) off[n] = carry;
}

__global__ void scatter_edges(const int* __restrict__ src, const int* __restrict__ dst,
                              int* __restrict__ cur, int* __restrict__ eidx, int E)
{
    int e = blockIdx.x * blockDim.x + threadIdx.x;
    if (e < E) {
        int p = atomicAdd(&cur[dst[e]], 1);
        eidx[p] = src[e];
    }
}

// ---------------------------------------------------------------------------
// Segment mean over bf16 h (D=512) + fp32 residual add; writes GEMM2's
// A-planes [mt][kt(16)][r(128)][p(4)], p = o^((r>>1)&3). One wave per dst
// row; 2-edge unrolled gather (2 loads in flight; accumulation order kept).
// ---------------------------------------------------------------------------
__global__ __launch_bounds__(256)
void seg_mean_split(const unsigned short* __restrict__ h, const int* __restrict__ off,
                    const int* __restrict__ eidx, const float* __restrict__ addin,
                    uint4* __restrict__ out, int n_dst, int n_pad)
{
    const int wid = blockIdx.x * 4 + (threadIdx.x >> 6);
    const int lane = threadIdx.x & 63;
    if (wid >= n_pad) return;
    uint4 v = {0u, 0u, 0u, 0u};
    if (wid < n_dst) {
        const int e0 = off[wid], e1 = off[wid + 1];
        float s[8];
#pragma unroll
        for (int i = 0; i < 8; ++i) s[i] = 0.f;
        int e = e0;
        for (; e + 1 < e1; e += 2) {
            const uint4 va = *((const uint4*)(h + (size_t)eidx[e] * 512) + lane);
            const uint4 vb = *((const uint4*)(h + (size_t)eidx[e + 1] * 512) + lane);
            const uint ua[4] = {va.x, va.y, va.z, va.w};
            const uint ub[4] = {vb.x, vb.y, vb.z, vb.w};
#pragma unroll
            for (int i = 0; i < 4; ++i) {
                s[2 * i]     += __uint_as_float(ua[i] << 16);
                s[2 * i + 1] += __uint_as_float(ua[i] & 0xFFFF0000u);
            }
#pragma unroll
            for (int i = 0; i < 4; ++i) {
                s[2 * i]     += __uint_as_float(ub[i] << 16);
                s[2 * i + 1] += __uint_as_float(ub[i] & 0xFFFF0000u);
            }
        }
        if (e < e1) {
            const uint4 va = *((const uint4*)(h + (size_t)eidx[e] * 512) + lane);
            const uint ua[4] = {va.x, va.y, va.z, va.w};
#pragma unroll
            for (int i = 0; i < 4; ++i) {
                s[2 * i]     += __uint_as_float(ua[i] << 16);
                s[2 * i + 1] += __uint_as_float(ua[i] & 0xFFFF0000u);
            }
        }
        const float sc = 1.0f / (float)((e1 - e0) > 0 ? (e1 - e0) : 1);
        const float* ad = addin + (size_t)wid * 512 + lane * 8;
        float4 d0 = *(const float4*)ad;
        float4 d1 = *(const float4*)(ad + 4);
        v.x = cvt2bf(s[0] * sc + d0.x, s[1] * sc + d0.y);
        v.y = cvt2bf(s[2] * sc + d0.z, s[3] * sc + d0.w);
        v.z = cvt2bf(s[4] * sc + d1.x, s[5] * sc + d1.y);
        v.w = cvt2bf(s[6] * sc + d1.z, s[7] * sc + d1.w);
    }
    const int mt = wid >> 7, r = wid & 127;
    const int kt = lane >> 2, o = lane & 3;
    out[((size_t)mt * 16 + kt) * 512 + r * 4 + (o ^ ((r >> 1) & 3))] = v;
}

// ---------------------------------------------------------------------------
// Segment mean over bf16 h (D=1024) + fp32 residual add -> fp32 out (agg1);
// 2-edge unrolled gather.
// ---------------------------------------------------------------------------
__global__ __launch_bounds__(256)
void seg_mean_add4(const unsigned short* __restrict__ h, const int* __restrict__ off,
                   const int* __restrict__ eidx, const float* __restrict__ addin,
                   float* __restrict__ out, int n_dst)
{
    const int wid = blockIdx.x * 4 + (threadIdx.x >> 6);
    const int lane = threadIdx.x & 63;
    if (wid >= n_dst) return;
    const int e0 = off[wid], e1 = off[wid + 1];
    float s[16];
#pragma unroll
    for (int i = 0; i < 16; ++i) s[i] = 0.f;
    int e = e0;
    for (; e + 1 < e1; e += 2) {
        const uint4* rowa = (const uint4*)(h + (size_t)eidx[e] * 1024);
        const uint4* rowb = (const uint4*)(h + (size_t)eidx[e + 1] * 1024);
        uint4 va[2] = {rowa[lane], rowa[lane + 64]};
        uint4 vb[2] = {rowb[lane], rowb[lane + 64]};
#pragma unroll
        for (int half = 0; half < 2; ++half) {
            const uint u[4] = {va[half].x, va[half].y, va[half].z, va[half].w};
#pragma unroll
            for (int i = 0; i < 4; ++i) {
                s[8 * half + 2 * i]     += __uint_as_float(u[i] << 16);
                s[8 * half + 2 * i + 1] += __uint_as_float(u[i] & 0xFFFF0000u);
            }
        }
#pragma unroll
        for (int half = 0; half < 2; ++half) {
            const uint u[4] = {vb[half].x, vb[half].y, vb[half].z, vb[half].w};
#pragma unroll
            for (int i = 0; i < 4; ++i) {
                s[8 * half + 2 * i]     += __uint_as_float(u[i] << 16);
                s[8 * half + 2 * i + 1] += __uint_as_float(u[i] & 0xFFFF0000u);
            }
        }
    }
    if (e < e1) {
        const uint4* row = (const uint4*)(h + (size_t)eidx[e] * 1024);
#pragma unroll
        for (int half = 0; half < 2; ++half) {
            const uint4 v = row[lane + 64 * half];
            const uint u[4] = {v.x, v.y, v.z, v.w};
#pragma unroll
            for (int i = 0; i < 4; ++i) {
                s[8 * half + 2 * i]     += __uint_as_float(u[i] << 16);
                s[8 * half + 2 * i + 1] += __uint_as_float(u[i] & 0xFFFF0000u);
            }
        }
    }
    const float sc = 1.0f / (float)((e1 - e0) > 0 ? (e1 - e0) : 1);
#pragma unroll
    for (int half = 0; half < 2; ++half) {
        const float* ad = addin + (size_t)wid * 1024 + half * 512 + lane * 8;
        float* o = out + (size_t)wid * 1024 + half * 512 + lane * 8;
        float4 d0 = *(const float4*)ad;
        float4 d1 = *(const float4*)(ad + 4);
        float4 r0, r1;
        r0.x = s[8*half+0] * sc + d0.x; r0.y = s[8*half+1] * sc + d0.y;
        r0.z = s[8*half+2] * sc + d0.z; r0.w = s[8*half+3] * sc + d0.w;
        r1.x = s[8*half+4] * sc + d1.x; r1.y = s[8*half+5] * sc + d1.y;
        r1.z = s[8*half+6] * sc + d1.z; r1.w = s[8*half+7] * sc + d1.w;
        *(float4*)o = r0;
        *(float4*)(o + 4) = r1;
    }
}

// ---------------------------------------------------------------------------
extern "C" void kernel_launch(void* const* d_in, const int* in_sizes, int n_in,
                              void* d_out, int out_size, void* d_ws, size_t ws_size,
                              hipStream_t stream)
{
    const float* feats   = (const float*)d_in[0];
    const float* h0_hist = (const float*)d_in[1];
    const float* agg_h0  = (const float*)d_in[2];
    const float* h1_hist = (const float*)d_in[3];
    const float* agg_h1  = (const float*)d_in[4];
    const float* W0 = (const float*)d_in[5];
    const float* b0 = (const float*)d_in[6];
    const float* W1 = (const float*)d_in[7];
    const float* b1 = (const float*)d_in[8];
    const float* W2 = (const float*)d_in[9];
    const float* b2 = (const float*)d_in[10];
    const int* src0 = (const int*)d_in[11];
    const int* dst0 = (const int*)d_in[12];
    const int* src1 = (const int*)d_in[13];
    const int* dst1 = (const int*)d_in[14];

    const int MT1 = 782;                       // ceil(100000/128)
    const int MT2 = 196;                       // ceil(25000/128)

    const size_t h0B   = ((size_t)N0c * 512 * 2 + 255) & ~(size_t)255;   // bf16 h0 (h1cat overlays)
    const size_t a2B   = (size_t)MT2 * 16 * 512 * 16;                    // 25.7 MB (A2 planes)
    const size_t agg1B = (size_t)N2c * 1024 * 4;                         // 20.5 MB
    const size_t wsB   = 32768 * 16;                                     // 512 KB per weight plane

    char* ws = (char*)d_ws;
    unsigned short* h0 = (unsigned short*)ws;
    unsigned short* h1cat = h0;                              ws += h0B;
    uint4* A2s    = (uint4*)ws;                              ws += a2B;
    float* agg1   = (float*)ws;                              ws += agg1B;
    uint4* Ws0    = (uint4*)ws;                              ws += wsB;
    uint4* Ws1    = (uint4*)ws;                              ws += wsB;
    int* deg0  = (int*)ws;  ws += sizeof(int) * N1c;
    int* off0  = (int*)ws;  ws += sizeof(int) * (N1c + 1);
    int* cur0  = (int*)ws;  ws += sizeof(int) * N1c;
    int* eidx0 = (int*)ws;  ws += sizeof(int) * E0c;
    int* deg1  = (int*)ws;  ws += sizeof(int) * N2c;
    int* off1  = (int*)ws;  ws += sizeof(int) * (N2c + 1);
    int* cur1  = (int*)ws;  ws += sizeof(int) * N2c;
    int* eidx1 = (int*)ws;

    hipMemsetAsync(deg0, 0, sizeof(int) * N1c, stream);
    hipMemsetAsync(deg1, 0, sizeof(int) * N2c, stream);

    // weight planes + CSR level 0 (independent of GEMM1)
    presplit_w<<<128, 256, 0, stream>>>(W0, Ws0);
    presplit_w<<<128, 256, 0, stream>>>(W1, Ws1);
    count_deg<<<(E0c + 255) / 256, 256, 0, stream>>>(dst0, deg0, E0c);
    exscan<<<1, 1024, 0, stream>>>(deg0, off0, cur0, N1c);
    scatter_edges<<<(E0c + 255) / 256, 256, 0, stream>>>(src0, dst0, cur0, eidx0, E0c);

    // layer 0: h0 = bf16(relu(feats @ W0^T + b0) - h0_hist)
    // A = raw fp32 feats staged by DMA (permuted source), cvt at fragment-read
    gemm_fused<0, 0><<<MT1 * 2, 512, 0, stream>>>(feats, nullptr, Ws0, b0, h0_hist, h0, N0c, MT1 * 2);

    // agg0 = segment_mean(h0) + agg_h0, written as GEMM2 A-planes
    seg_mean_split<<<(MT2 * 128) / 4, 256, 0, stream>>>(h0, off0, eidx0, agg_h0, A2s, N1c, MT2 * 128);

    // CSR level 1
    count_deg<<<(E1c + 255) / 256, 256, 0, stream>>>(dst1, deg1, E1c);
    exscan<<<1, 1024, 0, stream>>>(deg1, off1, cur1, N2c);
    scatter_edges<<<(E1c + 255) / 256, 256, 0, stream>>>(src1, dst1, cur1, eidx1, E1c);

    // layer 1: h1cat = bf16([h1 | relu(h1)] - h1_hist), h1 = agg0 @ W1^T + b1
    gemm_fused<1, 1><<<MT2 * 2, 512, 0, stream>>>(nullptr, A2s, Ws1, b1, h1_hist, h1cat, N1c, MT2 * 2);

    // agg1 = segment_mean(h1cat) + agg_h1  (fp32)
    seg_mean_add4<<<(N2c + 3) / 4, 256, 0, stream>>>(h1cat, off1, eidx1, agg_h1, agg1, N2c);

    // classifier: out = agg1 @ W2^T + b2
    gemm64<<<(N2c + 63) / 64, 256, 0, stream>>>(agg1, W2, b2, (float*)d_out, N2c);
}